// Round 11
// baseline (370.625 us; speedup 1.0000x reference)
//
#include <hip/hip_runtime.h>
#include <hip/hip_bf16.h>
#include <math.h>

// Problem constants (match reference)
#define E_EDGES 262144
#define NBUCKET 8192
#define DEG     32
#define FDIM    128   // in_feats == out_feats == 128
#define ENC_TILES 4   // row-tiles of 128 per encode block

typedef float f32x4 __attribute__((ext_vector_type(4)));
typedef short s16x8 __attribute__((ext_vector_type(8)));
typedef short s16x4 __attribute__((ext_vector_type(4)));

typedef const __attribute__((address_space(1))) unsigned g_u32;
typedef __attribute__((address_space(3))) unsigned l_u32;

__device__ __forceinline__ short f2bf(float f) {
    __hip_bfloat16 h = __float2bfloat16(f);      // RNE, HW cvt
    return *reinterpret_cast<short*>(&h);
}
__device__ __forceinline__ float bf2f(short s) {
    union { unsigned u; float f; } v; v.u = ((unsigned)(unsigned short)s) << 16;
    return v.f;
}

// LDS weight layout: row n (0..127), col k (0..127) bf16 at
//   byte = ((n<<8) + (k<<1)) ^ ((n&7)<<4)      (XOR swizzle on 16B granules)
__device__ __forceinline__ s16x8 read_wfrag(const short* w_lds, int n, int k0) {
    int byte = ((n << 8) + (k0 << 1)) ^ ((n & 7) << 4);
    return *reinterpret_cast<const s16x8*>(reinterpret_cast<const char*>(w_lds) + byte);
}

// f32 staging fallback (R1-style) for the no-workspace path
__device__ __forceinline__ void stage_w(short* w_lds, const float* __restrict__ Wg,
                                        int stride, int tid) {
    #pragma unroll
    for (int it = 0; it < 16; ++it) {
        int i  = it * 256 + tid;
        int n  = i >> 5;
        int k4 = (i & 31) << 2;
        const float4 v = *reinterpret_cast<const float4*>(Wg + (size_t)n * stride + k4);
        s16x4 h; h[0]=f2bf(v.x); h[1]=f2bf(v.y); h[2]=f2bf(v.z); h[3]=f2bf(v.w);
        int byte = ((n << 8) + (k4 << 1)) ^ ((n & 7) << 4);
        *reinterpret_cast<s16x4*>(reinterpret_cast<char*>(w_lds) + byte) = h;
    }
}

// DMA 32 KB of pre-swizzled bf16 weights into LDS (256-thread block).
__device__ __forceinline__ void dma_w32k(const short* __restrict__ gsw, short* lds, int tid) {
    const int lane = tid & 63, wid = tid >> 6;           // 4 waves
    const char* g = reinterpret_cast<const char*>(gsw);
    char* l = reinterpret_cast<char*>(lds);
    #pragma unroll
    for (int i = 0; i < 8; ++i) {
        const int off = i * 4096 + wid * 1024;           // + lane*16 by HW on LDS side
        __builtin_amdgcn_global_load_lds((g_u32*)(g + off + lane * 16),
                                         (l_u32*)(l + off), 16, 0, 0);
    }
}

// ---------------------------------------------------------------------------
// Prep: W_time/W_self/W_neigh f32 -> bf16 PRE-SWIZZLED (4 x 32 KB regions).
// ---------------------------------------------------------------------------
__global__ void prep_kernel(const float* __restrict__ W_time,
                            const float* __restrict__ W_self,
                            const float* __restrict__ W_neigh,
                            short* __restrict__ Wswz)
{
    const int t = blockIdx.x * 256 + threadIdx.x;        // 8192 threads
    const int region = t >> 11;
    const int chunk  = t & 2047;                         // 16B chunk within region
    const int n = chunk >> 4;
    const int c = chunk & 15;                            // k = c*8

    const float* src;
    if      (region == 0) src = W_time  + n * 256 + c * 8;
    else if (region == 1) src = W_time  + n * 256 + 128 + c * 8;
    else if (region == 2) src = W_self  + n * 128 + c * 8;
    else                  src = W_neigh + n * 128 + c * 8;

    const float4 lo = *reinterpret_cast<const float4*>(src);
    const float4 hi = *reinterpret_cast<const float4*>(src + 4);
    s16x8 h;
    h[0]=f2bf(lo.x); h[1]=f2bf(lo.y); h[2]=f2bf(lo.z); h[3]=f2bf(lo.w);
    h[4]=f2bf(hi.x); h[5]=f2bf(hi.y); h[6]=f2bf(hi.z); h[7]=f2bf(hi.w);

    const int byte = (region << 15) + ((((n << 8) + (c << 4)) ^ ((n & 7) << 4)));
    *reinterpret_cast<s16x8*>(reinterpret_cast<char*>(Wswz) + byte) = h;
}

// ---------------------------------------------------------------------------
// Phase 1 (R11): pipelined multi-tile encode. launch_bounds(512,1):
// empirically (R9: arg=4 -> 64 VGPR, R10: arg=2 -> 128 VGPR) the 2nd arg
// scaled the VGPR cap as workgroups/CU; arg=1 gives the 256-VGPR budget the
// 16 float4 prefetch banks need. LDS 64 KB -> 1 block/CU; latency hiding is
// the explicit prefetch, not TLP.
// ---------------------------------------------------------------------------
__global__ __launch_bounds__(512, 1)
void encode_kernel(const float* __restrict__ src_feat,
                   const float* __restrict__ dst_feat,
                   const float* __restrict__ ts,
                   const float* __restrict__ freq,
                   const float* __restrict__ ph,
                   const short* __restrict__ Wswz,     // regions 0,1 (64 KB)
                   const float* __restrict__ b_time,
                   short* __restrict__ enc_src,
                   short* __restrict__ enc_dst)
{
    __shared__ short w_lds[2][128 * 128];   // 64 KB: [0]=W1, [1]=W2 (swizzled)

    const int tid  = threadIdx.x;
    const int lane = tid & 63;
    const int wid  = tid >> 6;              // 0..7
    const int lrow = lane & 15;             // edge row within wave tile
    const int q    = lane >> 4;             // channel quadrant
    const int klo  = q << 3;
    const int base = blockIdx.x * (128 * ENC_TILES) + wid * 16 + lrow;

    // 1) DMA both W halves (64 KB): 8 waves x 8 x 1 KB
    {
        const char* g = reinterpret_cast<const char*>(Wswz);
        char* l = reinterpret_cast<char*>(&w_lds[0][0]);
        #pragma unroll
        for (int i = 0; i < 8; ++i) {
            const int off = i * 8192 + wid * 1024;
            __builtin_amdgcn_global_load_lds((g_u32*)(g + off + lane * 16),
                                             (l_u32*)(l + off), 16, 0, 0);
        }
    }

    // 2) issue tile-0 feat loads into the f32 banks
    float4 sf[8], df[8];
    {
        const float* ps = src_feat + (size_t)base * FDIM + klo;
        const float* pd = dst_feat + (size_t)base * FDIM + klo;
        #pragma unroll
        for (int kb = 0; kb < 4; ++kb) {
            sf[kb*2]   = *reinterpret_cast<const float4*>(ps + kb * 32);
            sf[kb*2+1] = *reinterpret_cast<const float4*>(ps + kb * 32 + 4);
            df[kb*2]   = *reinterpret_cast<const float4*>(pd + kb * 32);
            df[kb*2+1] = *reinterpret_cast<const float4*>(pd + kb * 32 + 4);
        }
    }
    float t_cur = ts[base];

    __syncthreads();   // W ready (also drains tile-0 loads)

    #pragma unroll
    for (int it = 0; it < ENC_TILES; ++it) {
        const int r = base + it * 128;

        // 3) cvt current banks -> bf16 fragments (frees the f32 banks)
        s16x8 as_[4], ad_[4];
        #pragma unroll
        for (int kb = 0; kb < 4; ++kb) {
            s16x8 a, b;
            #pragma unroll
            for (int j = 0; j < 4; ++j) {
                a[j]   = f2bf(sf[kb*2][j]);   a[4+j] = f2bf(sf[kb*2+1][j]);
                b[j]   = f2bf(df[kb*2][j]);   b[4+j] = f2bf(df[kb*2+1][j]);
            }
            as_[kb] = a; ad_[kb] = b;
        }

        // 4) refill banks with NEXT tile's loads (land during this tile's
        //    cos+MFMA+stores; next iteration's cvt waits on them)
        float t_next = 0.f;
        if (it + 1 < ENC_TILES) {
            const int rn = r + 128;
            const float* ps = src_feat + (size_t)rn * FDIM + klo;
            const float* pd = dst_feat + (size_t)rn * FDIM + klo;
            #pragma unroll
            for (int kb = 0; kb < 4; ++kb) {
                sf[kb*2]   = *reinterpret_cast<const float4*>(ps + kb * 32);
                sf[kb*2+1] = *reinterpret_cast<const float4*>(ps + kb * 32 + 4);
                df[kb*2]   = *reinterpret_cast<const float4*>(pd + kb * 32);
                df[kb*2+1] = *reinterpret_cast<const float4*>(pd + kb * 32 + 4);
            }
            t_next = ts[rn];
        }

        // 5) time fragments for current tile
        s16x8 tf[4];
        #pragma unroll
        for (int kb = 0; kb < 4; ++kb) {
            s16x8 t;
            #pragma unroll
            for (int j = 0; j < 8; ++j) {
                const int k = kb * 32 + klo + j;
                t[j] = f2bf(__cosf(fmaf(t_cur, freq[k], ph[k])));
            }
            tf[kb] = t;
        }

        // 6) per-nt (swapped operands): packed 8B stores
        #pragma unroll
        for (int nt = 0; nt < 8; ++nt) {
            const int n = nt * 16 + lrow;
            f32x4 a = {0.f, 0.f, 0.f, 0.f};
            #pragma unroll
            for (int kb = 0; kb < 4; ++kb)
                a = __builtin_amdgcn_mfma_f32_16x16x32_bf16(
                        read_wfrag(w_lds[1], n, kb * 32 + klo), tf[kb], a, 0, 0, 0);
            f32x4 b = a;
            #pragma unroll
            for (int kb = 0; kb < 4; ++kb) {
                const s16x8 wf = read_wfrag(w_lds[0], n, kb * 32 + klo);
                a = __builtin_amdgcn_mfma_f32_16x16x32_bf16(wf, as_[kb], a, 0, 0, 0);
                b = __builtin_amdgcn_mfma_f32_16x16x32_bf16(wf, ad_[kb], b, 0, 0, 0);
            }
            const int ch = nt * 16 + q * 4;
            const float4 bias4 = *reinterpret_cast<const float4*>(b_time + ch);
            s16x4 ss, sd;
            #pragma unroll
            for (int rr = 0; rr < 4; ++rr) {
                float es = a[rr] + bias4[rr]; es = es > 0.f ? es : 0.f;
                float ed = b[rr] + bias4[rr]; ed = ed > 0.f ? ed : 0.f;
                ss[rr] = f2bf(es); sd[rr] = f2bf(ed);
            }
            *reinterpret_cast<s16x4*>(enc_src + (size_t)r * FDIM + ch) = ss;
            *reinterpret_cast<s16x4*>(enc_dst + (size_t)r * FDIM + ch) = sd;
        }

        t_cur = t_next;
    }
}

// Fallback encode (R1 structure, f32 staging) if workspace lacks Wswz room.
__global__ __launch_bounds__(256, 2)
void encode_fallback(const float* __restrict__ src_feat,
                     const float* __restrict__ dst_feat,
                     const float* __restrict__ ts,
                     const float* __restrict__ freq,
                     const float* __restrict__ ph,
                     const float* __restrict__ W_time,
                     const float* __restrict__ b_time,
                     short* __restrict__ enc_src,
                     short* __restrict__ enc_dst)
{
    __shared__ short w_lds[128 * 128];
    const int tid  = threadIdx.x;
    const int lane = tid & 63;
    const int wid  = tid >> 6;
    const int r0   = blockIdx.x * 64 + wid * 16;
    const int lrow = lane & 15;
    const int klo  = (lane >> 4) << 3;

    stage_w(w_lds, W_time + 128, 256, tid);
    const float t_row = ts[r0 + lrow];
    s16x8 tf[4];
    #pragma unroll
    for (int kb = 0; kb < 4; ++kb) {
        const int k = kb * 32 + klo;
        s16x8 t;
        #pragma unroll
        for (int j = 0; j < 8; ++j)
            t[j] = f2bf(__cosf(fmaf(t_row, freq[k + j], ph[k + j])));
        tf[kb] = t;
    }
    __syncthreads();
    f32x4 S[8];
    #pragma unroll
    for (int nt = 0; nt < 8; ++nt) {
        f32x4 a = {0.f, 0.f, 0.f, 0.f};
        #pragma unroll
        for (int kb = 0; kb < 4; ++kb)
            a = __builtin_amdgcn_mfma_f32_16x16x32_bf16(
                    tf[kb], read_wfrag(w_lds, nt * 16 + lrow, kb * 32 + klo), a, 0, 0, 0);
        S[nt] = a;
    }
    __syncthreads();
    stage_w(w_lds, W_time, 256, tid);
    __syncthreads();
    #pragma unroll
    for (int s = 0; s < 2; ++s) {
        const float* feat = s ? dst_feat : src_feat;
        short*       enc  = s ? enc_dst  : enc_src;
        s16x8 af[4];
        #pragma unroll
        for (int kb = 0; kb < 4; ++kb) {
            const float* p = feat + (size_t)(r0 + lrow) * FDIM + kb * 32 + klo;
            const float4 lo = *reinterpret_cast<const float4*>(p);
            const float4 hi = *reinterpret_cast<const float4*>(p + 4);
            s16x8 a;
            a[0]=f2bf(lo.x); a[1]=f2bf(lo.y); a[2]=f2bf(lo.z); a[3]=f2bf(lo.w);
            a[4]=f2bf(hi.x); a[5]=f2bf(hi.y); a[6]=f2bf(hi.z); a[7]=f2bf(hi.w);
            af[kb] = a;
        }
        #pragma unroll
        for (int nt = 0; nt < 8; ++nt) {
            f32x4 acc = S[nt];
            #pragma unroll
            for (int kb = 0; kb < 4; ++kb)
                acc = __builtin_amdgcn_mfma_f32_16x16x32_bf16(
                        af[kb], read_wfrag(w_lds, nt * 16 + lrow, kb * 32 + klo), acc, 0, 0, 0);
            const int col  = nt * 16 + lrow;
            const float bias = b_time[col];
            const int rbase = r0 + ((lane >> 4) << 2);
            #pragma unroll
            for (int r = 0; r < 4; ++r) {
                float e = acc[r] + bias;
                e = e > 0.f ? e : 0.f;
                enc[(size_t)(rbase + r) * FDIM + col] = f2bf(e);
            }
        }
    }
}

// ---------------------------------------------------------------------------
// Phase 2: R5 conv VERBATIM — per-bucket causal mean conv + scatter.
// ---------------------------------------------------------------------------
template<int DMA>
__global__ __launch_bounds__(256, 3)
void conv_kernel(const short* __restrict__ enc_src,
                 const short* __restrict__ enc_dst,
                 const short* __restrict__ Wswz_self,   // DMA=1
                 const short* __restrict__ Wswz_neigh,  // DMA=1
                 const float* __restrict__ W_self,      // DMA=0
                 const float* __restrict__ W_neigh,     // DMA=0
                 const float* __restrict__ b_self,
                 const float* __restrict__ b_neigh,
                 const int* __restrict__ src_perm,
                 const int* __restrict__ dst_perm,
                 const int* __restrict__ src_idx,
                 const int* __restrict__ dst_idx,
                 float* __restrict__ out)        // [2][E][128] f32
{
    __shared__ short w_lds[128 * 128];   // 32 KB: Wself -> Wneigh -> f32 epilogue
    __shared__ short hf[2][DEG * 128];   // 16 KB, swizzled rows
    __shared__ int   perm_s[2][DEG];
    __shared__ int   idx_s[2][DEG];
    __shared__ float bias_s[128];

    const int tid = threadIdx.x;
    const int g   = blockIdx.y;
    const int b0  = blockIdx.x * 2;

    const short* enc_self  = g ? enc_dst : enc_src;
    const short* enc_neigh = g ? enc_src : enc_dst;
    const int*   perm      = g ? dst_perm : src_perm;
    const int*   degi      = g ? dst_idx  : src_idx;
    float*       outg      = out + (size_t)g * E_EDGES * FDIM;

    if (DMA) dma_w32k(Wswz_self, w_lds, tid);

    if (tid < 64) {
        const int lb = tid >> 5, d = tid & 31;
        perm_s[lb][d] = perm[(b0 + lb) * DEG + d];
        idx_s[lb][d]  = degi[(b0 + lb) * DEG + d];
    } else if (tid < 192) {
        const int c = tid - 64;
        bias_s[c] = b_self[c] + b_neigh[c];
    }
    if (!DMA) stage_w(w_lds, W_self, 128, tid);
    __syncthreads();

    const int lane = tid & 63;
    const int wid  = tid >> 6;
    const int lb   = wid >> 1;
    const int mt   = wid & 1;
    const int lrow = lane & 15;
    const int klo  = (lane >> 4) << 3;
    const int row  = mt * 16 + lrow;

    // Issue pass-A self-gather FIRST (pass A then waits only these)
    s16x8 hsf[4];
    {
        const int e = perm_s[lb][row];
        const short* p = enc_self + (size_t)e * FDIM;
        #pragma unroll
        for (int kb = 0; kb < 4; ++kb)
            hsf[kb] = *reinterpret_cast<const s16x8*>(p + kb * 32 + klo);
    }

    // Issue ALL cumsum row gathers (independent; land during pass-A MFMA)
    const int lbc = tid >> 7;          // bucket for cumsum role
    const int c   = tid & 127;         // channel
    unsigned short cum[DEG];
    #pragma unroll
    for (int d = 0; d < DEG; ++d) {
        const int e = perm_s[lbc][d];
        cum[d] = *reinterpret_cast<const unsigned short*>(
                     enc_neigh + (size_t)e * FDIM + c);
    }

    // pass A: hs @ Wself^T
    f32x4 acc[8];
    #pragma unroll
    for (int nt = 0; nt < 8; ++nt) {
        f32x4 a = {0.f, 0.f, 0.f, 0.f};
        #pragma unroll
        for (int kb = 0; kb < 4; ++kb)
            a = __builtin_amdgcn_mfma_f32_16x16x32_bf16(
                    hsf[kb], read_wfrag(w_lds, nt * 16 + lrow, kb * 32 + klo), a, 0, 0, 0);
        acc[nt] = a;
    }

    // cumsum accumulate -> hf (values already in registers)
    {
        float run = 0.f;
        #pragma unroll
        for (int d = 0; d < DEG; ++d) {
            run += bf2f((short)cum[d]);
            const float inv = __builtin_amdgcn_rcpf((float)(idx_s[lbc][d] + 1));
            const int byte = ((d << 8) + (c << 1)) ^ ((d & 7) << 4);
            *reinterpret_cast<short*>(reinterpret_cast<char*>(hf[lbc]) + byte)
                = f2bf(run * inv);
        }
    }

    __syncthreads();
    if (DMA) dma_w32k(Wswz_neigh, w_lds, tid);
    else     stage_w(w_lds, W_neigh, 128, tid);
    __syncthreads();

    // pass B: hf[idx[row]] @ Wneigh^T
    s16x8 mff[4];
    {
        const int j = idx_s[lb][row];
        #pragma unroll
        for (int kb = 0; kb < 4; ++kb) {
            const int byte = ((j << 8) + ((kb * 32 + klo) << 1)) ^ ((j & 7) << 4);
            mff[kb] = *reinterpret_cast<const s16x8*>(
                          reinterpret_cast<const char*>(hf[lb]) + byte);
        }
    }
    #pragma unroll
    for (int nt = 0; nt < 8; ++nt) {
        f32x4 a = acc[nt];
        #pragma unroll
        for (int kb = 0; kb < 4; ++kb)
            a = __builtin_amdgcn_mfma_f32_16x16x32_bf16(
                    mff[kb], read_wfrag(w_lds, nt * 16 + lrow, kb * 32 + klo), a, 0, 0, 0);
        acc[nt] = a;
    }

    // epilogue: transpose via w_lds (now free) -> float4 scatter stores
    __syncthreads();
    {
        float* epl = reinterpret_cast<float*>(w_lds) + wid * 2048;  // 16x128 f32
        #pragma unroll
        for (int nt = 0; nt < 8; ++nt) {
            const int col = nt * 16 + lrow;
            const float bias = bias_s[col];
            #pragma unroll
            for (int r = 0; r < 4; ++r) {
                const int rtile = ((lane >> 4) << 2) + r;
                epl[rtile * 128 + col] = acc[nt][r] + bias;
            }
        }
        asm volatile("s_waitcnt lgkmcnt(0)" ::: "memory");
        __builtin_amdgcn_sched_barrier(0);
        #pragma unroll
        for (int i = 0; i < 8; ++i) {
            const int rtile = i * 2 + (lane >> 5);
            const int c4    = (lane & 31) * 4;
            const f32x4 v = *reinterpret_cast<const f32x4*>(epl + rtile * 128 + c4);
            const int e = perm_s[lb][mt * 16 + rtile];
            *reinterpret_cast<f32x4*>(outg + (size_t)e * FDIM + c4) = v;
        }
    }
}

extern "C" void kernel_launch(void* const* d_in, const int* in_sizes, int n_in,
                              void* d_out, int out_size, void* d_ws, size_t ws_size,
                              hipStream_t stream) {
    (void)in_sizes; (void)n_in; (void)out_size;

    const float* src_feat = (const float*)d_in[0];
    const float* dst_feat = (const float*)d_in[1];
    const float* ts       = (const float*)d_in[2];
    const float* freq     = (const float*)d_in[3];
    const float* ph       = (const float*)d_in[4];
    const float* W_time   = (const float*)d_in[5];
    const float* b_time   = (const float*)d_in[6];
    const float* W_self   = (const float*)d_in[7];
    const float* b_self   = (const float*)d_in[8];
    const float* W_neigh  = (const float*)d_in[9];
    const float* b_neigh  = (const float*)d_in[10];
    const int*   src_perm = (const int*)d_in[11];
    const int*   dst_perm = (const int*)d_in[12];
    const int*   src_idx  = (const int*)d_in[13];
    const int*   dst_idx  = (const int*)d_in[14];

    // workspace: enc_src, enc_dst bf16 [E][128] (128 MiB) + Wswz (128 KiB)
    short* enc_src = (short*)d_ws;
    short* enc_dst = enc_src + (size_t)E_EDGES * FDIM;
    short* Wswz    = enc_dst + (size_t)E_EDGES * FDIM;
    const size_t need = (size_t)E_EDGES * FDIM * 2 * 2 + 4 * 32768;

    if (ws_size >= need) {
        prep_kernel<<<dim3(32), dim3(256), 0, stream>>>(W_time, W_self, W_neigh, Wswz);
        encode_kernel<<<dim3(E_EDGES / (128 * ENC_TILES)), dim3(512), 0, stream>>>(
            src_feat, dst_feat, ts, freq, ph, Wswz, b_time, enc_src, enc_dst);
        conv_kernel<1><<<dim3(NBUCKET / 2, 2), dim3(256), 0, stream>>>(
            enc_src, enc_dst, Wswz + 2 * 16384, Wswz + 3 * 16384, W_self, W_neigh,
            b_self, b_neigh, src_perm, dst_perm, src_idx, dst_idx, (float*)d_out);
    } else {
        encode_fallback<<<dim3(E_EDGES / 64), dim3(256), 0, stream>>>(
            src_feat, dst_feat, ts, freq, ph, W_time, b_time, enc_src, enc_dst);
        conv_kernel<0><<<dim3(NBUCKET / 2, 2), dim3(256), 0, stream>>>(
            enc_src, enc_dst, (const short*)nullptr, (const short*)nullptr,
            W_self, W_neigh, b_self, b_neigh,
            src_perm, dst_perm, src_idx, dst_idx, (float*)d_out);
    }
}

// Round 12
// 279.691 us; speedup vs baseline: 1.3251x; 1.3251x over previous
//
#include <hip/hip_runtime.h>
#include <hip/hip_bf16.h>
#include <math.h>

// Problem constants (match reference)
#define E_EDGES 262144
#define NBUCKET 8192
#define DEG     32
#define FDIM    128   // in_feats == out_feats == 128
#define ENC_TILES 4   // row-tiles of 64 per encode block (256 thr)

typedef float f32x4 __attribute__((ext_vector_type(4)));
typedef short s16x8 __attribute__((ext_vector_type(8)));
typedef short s16x4 __attribute__((ext_vector_type(4)));

typedef const __attribute__((address_space(1))) unsigned g_u32;
typedef __attribute__((address_space(3))) unsigned l_u32;

__device__ __forceinline__ short f2bf(float f) {
    __hip_bfloat16 h = __float2bfloat16(f);      // RNE, HW cvt
    return *reinterpret_cast<short*>(&h);
}
__device__ __forceinline__ float bf2f(short s) {
    union { unsigned u; float f; } v; v.u = ((unsigned)(unsigned short)s) << 16;
    return v.f;
}

// LDS weight layout: row n (0..127), col k (0..127) bf16 at
//   byte = ((n<<8) + (k<<1)) ^ ((n&7)<<4)      (XOR swizzle on 16B granules)
__device__ __forceinline__ s16x8 read_wfrag(const short* w_lds, int n, int k0) {
    int byte = ((n << 8) + (k0 << 1)) ^ ((n & 7) << 4);
    return *reinterpret_cast<const s16x8*>(reinterpret_cast<const char*>(w_lds) + byte);
}

// f32 staging fallback (R1-style) for the no-workspace path
__device__ __forceinline__ void stage_w(short* w_lds, const float* __restrict__ Wg,
                                        int stride, int tid) {
    #pragma unroll
    for (int it = 0; it < 16; ++it) {
        int i  = it * 256 + tid;
        int n  = i >> 5;
        int k4 = (i & 31) << 2;
        const float4 v = *reinterpret_cast<const float4*>(Wg + (size_t)n * stride + k4);
        s16x4 h; h[0]=f2bf(v.x); h[1]=f2bf(v.y); h[2]=f2bf(v.z); h[3]=f2bf(v.w);
        int byte = ((n << 8) + (k4 << 1)) ^ ((n & 7) << 4);
        *reinterpret_cast<s16x4*>(reinterpret_cast<char*>(w_lds) + byte) = h;
    }
}

// DMA 32 KB of pre-swizzled bf16 weights into LDS (256-thread block).
__device__ __forceinline__ void dma_w32k(const short* __restrict__ gsw, short* lds, int tid) {
    const int lane = tid & 63, wid = tid >> 6;           // 4 waves
    const char* g = reinterpret_cast<const char*>(gsw);
    char* l = reinterpret_cast<char*>(lds);
    #pragma unroll
    for (int i = 0; i < 8; ++i) {
        const int off = i * 4096 + wid * 1024;           // + lane*16 by HW on LDS side
        __builtin_amdgcn_global_load_lds((g_u32*)(g + off + lane * 16),
                                         (l_u32*)(l + off), 16, 0, 0);
    }
}

// ---------------------------------------------------------------------------
// Prep: W_time/W_self/W_neigh f32 -> bf16 PRE-SWIZZLED (4 x 32 KB regions).
// ---------------------------------------------------------------------------
__global__ void prep_kernel(const float* __restrict__ W_time,
                            const float* __restrict__ W_self,
                            const float* __restrict__ W_neigh,
                            short* __restrict__ Wswz)
{
    const int t = blockIdx.x * 256 + threadIdx.x;        // 8192 threads
    const int region = t >> 11;
    const int chunk  = t & 2047;                         // 16B chunk within region
    const int n = chunk >> 4;
    const int c = chunk & 15;                            // k = c*8

    const float* src;
    if      (region == 0) src = W_time  + n * 256 + c * 8;
    else if (region == 1) src = W_time  + n * 256 + 128 + c * 8;
    else if (region == 2) src = W_self  + n * 128 + c * 8;
    else                  src = W_neigh + n * 128 + c * 8;

    const float4 lo = *reinterpret_cast<const float4*>(src);
    const float4 hi = *reinterpret_cast<const float4*>(src + 4);
    s16x8 h;
    h[0]=f2bf(lo.x); h[1]=f2bf(lo.y); h[2]=f2bf(lo.z); h[3]=f2bf(lo.w);
    h[4]=f2bf(hi.x); h[5]=f2bf(hi.y); h[6]=f2bf(hi.z); h[7]=f2bf(hi.w);

    const int byte = (region << 15) + ((((n << 8) + (c << 4)) ^ ((n & 7) << 4)));
    *reinterpret_cast<s16x8*>(reinterpret_cast<char*>(Wswz) + byte) = h;
}

// ---------------------------------------------------------------------------
// Phase 1 (R12): pipelined multi-tile encode on 256-THREAD blocks.
// R9-R11 showed 512-thr blocks are hard-capped at 128 VGPR (2nd launch-bounds
// arg scaled as 256/arg, floor 128) -> the 16 float4 prefetch banks spilled.
// 4-wave blocks with (256,1) get the full 256-VGPR budget. LDS 64 KB ->
// 2 blocks/CU = 8 waves/CU at <=256 VGPR (m69). Explicit next-tile prefetch
// hides HBM latency under cos+MFMA+stores; W DMA'd once; one barrier total.
// ---------------------------------------------------------------------------
__global__ __launch_bounds__(256, 1)
void encode_kernel(const float* __restrict__ src_feat,
                   const float* __restrict__ dst_feat,
                   const float* __restrict__ ts,
                   const float* __restrict__ freq,
                   const float* __restrict__ ph,
                   const short* __restrict__ Wswz,     // regions 0,1 (64 KB)
                   const float* __restrict__ b_time,
                   short* __restrict__ enc_src,
                   short* __restrict__ enc_dst)
{
    __shared__ short w_lds[2][128 * 128];   // 64 KB: [0]=W1, [1]=W2 (swizzled)

    const int tid  = threadIdx.x;
    const int lane = tid & 63;
    const int wid  = tid >> 6;              // 0..3
    const int lrow = lane & 15;             // edge row within wave tile
    const int q    = lane >> 4;             // channel quadrant
    const int klo  = q << 3;
    const int base = blockIdx.x * (64 * ENC_TILES) + wid * 16 + lrow;

    // 1) DMA both W halves (64 KB): 256 thr x 16 x 16B
    {
        const char* g = reinterpret_cast<const char*>(Wswz);
        char* l = reinterpret_cast<char*>(&w_lds[0][0]);
        #pragma unroll
        for (int i = 0; i < 16; ++i) {
            const int off = i * 4096 + wid * 1024;
            __builtin_amdgcn_global_load_lds((g_u32*)(g + off + lane * 16),
                                             (l_u32*)(l + off), 16, 0, 0);
        }
    }

    // 2) issue tile-0 feat loads into the f32 banks
    float4 sf[8], df[8];
    {
        const float* ps = src_feat + (size_t)base * FDIM + klo;
        const float* pd = dst_feat + (size_t)base * FDIM + klo;
        #pragma unroll
        for (int kb = 0; kb < 4; ++kb) {
            sf[kb*2]   = *reinterpret_cast<const float4*>(ps + kb * 32);
            sf[kb*2+1] = *reinterpret_cast<const float4*>(ps + kb * 32 + 4);
            df[kb*2]   = *reinterpret_cast<const float4*>(pd + kb * 32);
            df[kb*2+1] = *reinterpret_cast<const float4*>(pd + kb * 32 + 4);
        }
    }
    float t_cur = ts[base];

    __syncthreads();   // W ready (also drains tile-0 loads)

    #pragma unroll
    for (int it = 0; it < ENC_TILES; ++it) {
        const int r = base + it * 64;

        // 3) cvt current banks -> bf16 fragments (frees the f32 banks)
        s16x8 as_[4], ad_[4];
        #pragma unroll
        for (int kb = 0; kb < 4; ++kb) {
            s16x8 a, b;
            #pragma unroll
            for (int j = 0; j < 4; ++j) {
                a[j]   = f2bf(sf[kb*2][j]);   a[4+j] = f2bf(sf[kb*2+1][j]);
                b[j]   = f2bf(df[kb*2][j]);   b[4+j] = f2bf(df[kb*2+1][j]);
            }
            as_[kb] = a; ad_[kb] = b;
        }

        // 4) refill banks with NEXT tile's loads (land during this tile's
        //    cos+MFMA+stores; next iteration's cvt waits on them)
        float t_next = 0.f;
        if (it + 1 < ENC_TILES) {
            const int rn = r + 64;
            const float* ps = src_feat + (size_t)rn * FDIM + klo;
            const float* pd = dst_feat + (size_t)rn * FDIM + klo;
            #pragma unroll
            for (int kb = 0; kb < 4; ++kb) {
                sf[kb*2]   = *reinterpret_cast<const float4*>(ps + kb * 32);
                sf[kb*2+1] = *reinterpret_cast<const float4*>(ps + kb * 32 + 4);
                df[kb*2]   = *reinterpret_cast<const float4*>(pd + kb * 32);
                df[kb*2+1] = *reinterpret_cast<const float4*>(pd + kb * 32 + 4);
            }
            t_next = ts[rn];
        }

        // 5) time fragments for current tile
        s16x8 tf[4];
        #pragma unroll
        for (int kb = 0; kb < 4; ++kb) {
            s16x8 t;
            #pragma unroll
            for (int j = 0; j < 8; ++j) {
                const int k = kb * 32 + klo + j;
                t[j] = f2bf(__cosf(fmaf(t_cur, freq[k], ph[k])));
            }
            tf[kb] = t;
        }

        // 6) per-nt (swapped operands): packed 8B stores
        #pragma unroll
        for (int nt = 0; nt < 8; ++nt) {
            const int n = nt * 16 + lrow;
            f32x4 a = {0.f, 0.f, 0.f, 0.f};
            #pragma unroll
            for (int kb = 0; kb < 4; ++kb)
                a = __builtin_amdgcn_mfma_f32_16x16x32_bf16(
                        read_wfrag(w_lds[1], n, kb * 32 + klo), tf[kb], a, 0, 0, 0);
            f32x4 b = a;
            #pragma unroll
            for (int kb = 0; kb < 4; ++kb) {
                const s16x8 wf = read_wfrag(w_lds[0], n, kb * 32 + klo);
                a = __builtin_amdgcn_mfma_f32_16x16x32_bf16(wf, as_[kb], a, 0, 0, 0);
                b = __builtin_amdgcn_mfma_f32_16x16x32_bf16(wf, ad_[kb], b, 0, 0, 0);
            }
            const int ch = nt * 16 + q * 4;
            const float4 bias4 = *reinterpret_cast<const float4*>(b_time + ch);
            s16x4 ss, sd;
            #pragma unroll
            for (int rr = 0; rr < 4; ++rr) {
                float es = a[rr] + bias4[rr]; es = es > 0.f ? es : 0.f;
                float ed = b[rr] + bias4[rr]; ed = ed > 0.f ? ed : 0.f;
                ss[rr] = f2bf(es); sd[rr] = f2bf(ed);
            }
            *reinterpret_cast<s16x4*>(enc_src + (size_t)r * FDIM + ch) = ss;
            *reinterpret_cast<s16x4*>(enc_dst + (size_t)r * FDIM + ch) = sd;
        }

        t_cur = t_next;
    }
}

// Fallback encode (R1 structure, f32 staging) if workspace lacks Wswz room.
__global__ __launch_bounds__(256, 2)
void encode_fallback(const float* __restrict__ src_feat,
                     const float* __restrict__ dst_feat,
                     const float* __restrict__ ts,
                     const float* __restrict__ freq,
                     const float* __restrict__ ph,
                     const float* __restrict__ W_time,
                     const float* __restrict__ b_time,
                     short* __restrict__ enc_src,
                     short* __restrict__ enc_dst)
{
    __shared__ short w_lds[128 * 128];
    const int tid  = threadIdx.x;
    const int lane = tid & 63;
    const int wid  = tid >> 6;
    const int r0   = blockIdx.x * 64 + wid * 16;
    const int lrow = lane & 15;
    const int klo  = (lane >> 4) << 3;

    stage_w(w_lds, W_time + 128, 256, tid);
    const float t_row = ts[r0 + lrow];
    s16x8 tf[4];
    #pragma unroll
    for (int kb = 0; kb < 4; ++kb) {
        const int k = kb * 32 + klo;
        s16x8 t;
        #pragma unroll
        for (int j = 0; j < 8; ++j)
            t[j] = f2bf(__cosf(fmaf(t_row, freq[k + j], ph[k + j])));
        tf[kb] = t;
    }
    __syncthreads();
    f32x4 S[8];
    #pragma unroll
    for (int nt = 0; nt < 8; ++nt) {
        f32x4 a = {0.f, 0.f, 0.f, 0.f};
        #pragma unroll
        for (int kb = 0; kb < 4; ++kb)
            a = __builtin_amdgcn_mfma_f32_16x16x32_bf16(
                    tf[kb], read_wfrag(w_lds, nt * 16 + lrow, kb * 32 + klo), a, 0, 0, 0);
        S[nt] = a;
    }
    __syncthreads();
    stage_w(w_lds, W_time, 256, tid);
    __syncthreads();
    #pragma unroll
    for (int s = 0; s < 2; ++s) {
        const float* feat = s ? dst_feat : src_feat;
        short*       enc  = s ? enc_dst  : enc_src;
        s16x8 af[4];
        #pragma unroll
        for (int kb = 0; kb < 4; ++kb) {
            const float* p = feat + (size_t)(r0 + lrow) * FDIM + kb * 32 + klo;
            const float4 lo = *reinterpret_cast<const float4*>(p);
            const float4 hi = *reinterpret_cast<const float4*>(p + 4);
            s16x8 a;
            a[0]=f2bf(lo.x); a[1]=f2bf(lo.y); a[2]=f2bf(lo.z); a[3]=f2bf(lo.w);
            a[4]=f2bf(hi.x); a[5]=f2bf(hi.y); a[6]=f2bf(hi.z); a[7]=f2bf(hi.w);
            af[kb] = a;
        }
        #pragma unroll
        for (int nt = 0; nt < 8; ++nt) {
            f32x4 acc = S[nt];
            #pragma unroll
            for (int kb = 0; kb < 4; ++kb)
                acc = __builtin_amdgcn_mfma_f32_16x16x32_bf16(
                        af[kb], read_wfrag(w_lds, nt * 16 + lrow, kb * 32 + klo), acc, 0, 0, 0);
            const int col  = nt * 16 + lrow;
            const float bias = b_time[col];
            const int rbase = r0 + ((lane >> 4) << 2);
            #pragma unroll
            for (int r = 0; r < 4; ++r) {
                float e = acc[r] + bias;
                e = e > 0.f ? e : 0.f;
                enc[(size_t)(rbase + r) * FDIM + col] = f2bf(e);
            }
        }
    }
}

// ---------------------------------------------------------------------------
// Phase 2: R5 conv VERBATIM — per-bucket causal mean conv + scatter.
// ---------------------------------------------------------------------------
template<int DMA>
__global__ __launch_bounds__(256, 3)
void conv_kernel(const short* __restrict__ enc_src,
                 const short* __restrict__ enc_dst,
                 const short* __restrict__ Wswz_self,   // DMA=1
                 const short* __restrict__ Wswz_neigh,  // DMA=1
                 const float* __restrict__ W_self,      // DMA=0
                 const float* __restrict__ W_neigh,     // DMA=0
                 const float* __restrict__ b_self,
                 const float* __restrict__ b_neigh,
                 const int* __restrict__ src_perm,
                 const int* __restrict__ dst_perm,
                 const int* __restrict__ src_idx,
                 const int* __restrict__ dst_idx,
                 float* __restrict__ out)        // [2][E][128] f32
{
    __shared__ short w_lds[128 * 128];   // 32 KB: Wself -> Wneigh -> f32 epilogue
    __shared__ short hf[2][DEG * 128];   // 16 KB, swizzled rows
    __shared__ int   perm_s[2][DEG];
    __shared__ int   idx_s[2][DEG];
    __shared__ float bias_s[128];

    const int tid = threadIdx.x;
    const int g   = blockIdx.y;
    const int b0  = blockIdx.x * 2;

    const short* enc_self  = g ? enc_dst : enc_src;
    const short* enc_neigh = g ? enc_src : enc_dst;
    const int*   perm      = g ? dst_perm : src_perm;
    const int*   degi      = g ? dst_idx  : src_idx;
    float*       outg      = out + (size_t)g * E_EDGES * FDIM;

    if (DMA) dma_w32k(Wswz_self, w_lds, tid);

    if (tid < 64) {
        const int lb = tid >> 5, d = tid & 31;
        perm_s[lb][d] = perm[(b0 + lb) * DEG + d];
        idx_s[lb][d]  = degi[(b0 + lb) * DEG + d];
    } else if (tid < 192) {
        const int c = tid - 64;
        bias_s[c] = b_self[c] + b_neigh[c];
    }
    if (!DMA) stage_w(w_lds, W_self, 128, tid);
    __syncthreads();

    const int lane = tid & 63;
    const int wid  = tid >> 6;
    const int lb   = wid >> 1;
    const int mt   = wid & 1;
    const int lrow = lane & 15;
    const int klo  = (lane >> 4) << 3;
    const int row  = mt * 16 + lrow;

    // Issue pass-A self-gather FIRST (pass A then waits only these)
    s16x8 hsf[4];
    {
        const int e = perm_s[lb][row];
        const short* p = enc_self + (size_t)e * FDIM;
        #pragma unroll
        for (int kb = 0; kb < 4; ++kb)
            hsf[kb] = *reinterpret_cast<const s16x8*>(p + kb * 32 + klo);
    }

    // Issue ALL cumsum row gathers (independent; land during pass-A MFMA)
    const int lbc = tid >> 7;          // bucket for cumsum role
    const int c   = tid & 127;         // channel
    unsigned short cum[DEG];
    #pragma unroll
    for (int d = 0; d < DEG; ++d) {
        const int e = perm_s[lbc][d];
        cum[d] = *reinterpret_cast<const unsigned short*>(
                     enc_neigh + (size_t)e * FDIM + c);
    }

    // pass A: hs @ Wself^T
    f32x4 acc[8];
    #pragma unroll
    for (int nt = 0; nt < 8; ++nt) {
        f32x4 a = {0.f, 0.f, 0.f, 0.f};
        #pragma unroll
        for (int kb = 0; kb < 4; ++kb)
            a = __builtin_amdgcn_mfma_f32_16x16x32_bf16(
                    hsf[kb], read_wfrag(w_lds, nt * 16 + lrow, kb * 32 + klo), a, 0, 0, 0);
        acc[nt] = a;
    }

    // cumsum accumulate -> hf (values already in registers)
    {
        float run = 0.f;
        #pragma unroll
        for (int d = 0; d < DEG; ++d) {
            run += bf2f((short)cum[d]);
            const float inv = __builtin_amdgcn_rcpf((float)(idx_s[lbc][d] + 1));
            const int byte = ((d << 8) + (c << 1)) ^ ((d & 7) << 4);
            *reinterpret_cast<short*>(reinterpret_cast<char*>(hf[lbc]) + byte)
                = f2bf(run * inv);
        }
    }

    __syncthreads();
    if (DMA) dma_w32k(Wswz_neigh, w_lds, tid);
    else     stage_w(w_lds, W_neigh, 128, tid);
    __syncthreads();

    // pass B: hf[idx[row]] @ Wneigh^T
    s16x8 mff[4];
    {
        const int j = idx_s[lb][row];
        #pragma unroll
        for (int kb = 0; kb < 4; ++kb) {
            const int byte = ((j << 8) + ((kb * 32 + klo) << 1)) ^ ((j & 7) << 4);
            mff[kb] = *reinterpret_cast<const s16x8*>(
                          reinterpret_cast<const char*>(hf[lb]) + byte);
        }
    }
    #pragma unroll
    for (int nt = 0; nt < 8; ++nt) {
        f32x4 a = acc[nt];
        #pragma unroll
        for (int kb = 0; kb < 4; ++kb)
            a = __builtin_amdgcn_mfma_f32_16x16x32_bf16(
                    mff[kb], read_wfrag(w_lds, nt * 16 + lrow, kb * 32 + klo), a, 0, 0, 0);
        acc[nt] = a;
    }

    // epilogue: transpose via w_lds (now free) -> float4 scatter stores
    __syncthreads();
    {
        float* epl = reinterpret_cast<float*>(w_lds) + wid * 2048;  // 16x128 f32
        #pragma unroll
        for (int nt = 0; nt < 8; ++nt) {
            const int col = nt * 16 + lrow;
            const float bias = bias_s[col];
            #pragma unroll
            for (int r = 0; r < 4; ++r) {
                const int rtile = ((lane >> 4) << 2) + r;
                epl[rtile * 128 + col] = acc[nt][r] + bias;
            }
        }
        asm volatile("s_waitcnt lgkmcnt(0)" ::: "memory");
        __builtin_amdgcn_sched_barrier(0);
        #pragma unroll
        for (int i = 0; i < 8; ++i) {
            const int rtile = i * 2 + (lane >> 5);
            const int c4    = (lane & 31) * 4;
            const f32x4 v = *reinterpret_cast<const f32x4*>(epl + rtile * 128 + c4);
            const int e = perm_s[lb][mt * 16 + rtile];
            *reinterpret_cast<f32x4*>(outg + (size_t)e * FDIM + c4) = v;
        }
    }
}

extern "C" void kernel_launch(void* const* d_in, const int* in_sizes, int n_in,
                              void* d_out, int out_size, void* d_ws, size_t ws_size,
                              hipStream_t stream) {
    (void)in_sizes; (void)n_in; (void)out_size;

    const float* src_feat = (const float*)d_in[0];
    const float* dst_feat = (const float*)d_in[1];
    const float* ts       = (const float*)d_in[2];
    const float* freq     = (const float*)d_in[3];
    const float* ph       = (const float*)d_in[4];
    const float* W_time   = (const float*)d_in[5];
    const float* b_time   = (const float*)d_in[6];
    const float* W_self   = (const float*)d_in[7];
    const float* b_self   = (const float*)d_in[8];
    const float* W_neigh  = (const float*)d_in[9];
    const float* b_neigh  = (const float*)d_in[10];
    const int*   src_perm = (const int*)d_in[11];
    const int*   dst_perm = (const int*)d_in[12];
    const int*   src_idx  = (const int*)d_in[13];
    const int*   dst_idx  = (const int*)d_in[14];

    // workspace: enc_src, enc_dst bf16 [E][128] (128 MiB) + Wswz (128 KiB)
    short* enc_src = (short*)d_ws;
    short* enc_dst = enc_src + (size_t)E_EDGES * FDIM;
    short* Wswz    = enc_dst + (size_t)E_EDGES * FDIM;
    const size_t need = (size_t)E_EDGES * FDIM * 2 * 2 + 4 * 32768;

    if (ws_size >= need) {
        prep_kernel<<<dim3(32), dim3(256), 0, stream>>>(W_time, W_self, W_neigh, Wswz);
        encode_kernel<<<dim3(E_EDGES / (64 * ENC_TILES)), dim3(256), 0, stream>>>(
            src_feat, dst_feat, ts, freq, ph, Wswz, b_time, enc_src, enc_dst);
        conv_kernel<1><<<dim3(NBUCKET / 2, 2), dim3(256), 0, stream>>>(
            enc_src, enc_dst, Wswz + 2 * 16384, Wswz + 3 * 16384, W_self, W_neigh,
            b_self, b_neigh, src_perm, dst_perm, src_idx, dst_idx, (float*)d_out);
    } else {
        encode_fallback<<<dim3(E_EDGES / 64), dim3(256), 0, stream>>>(
            src_feat, dst_feat, ts, freq, ph, W_time, b_time, enc_src, enc_dst);
        conv_kernel<0><<<dim3(NBUCKET / 2, 2), dim3(256), 0, stream>>>(
            enc_src, enc_dst, (const short*)nullptr, (const short*)nullptr,
            W_self, W_neigh, b_self, b_neigh,
            src_perm, dst_perm, src_idx, dst_idx, (float*)d_out);
    }
}

// Round 13
// 238.695 us; speedup vs baseline: 1.5527x; 1.1718x over previous
//
#include <hip/hip_runtime.h>
#include <hip/hip_bf16.h>
#include <math.h>

// Problem constants (match reference)
#define E_EDGES 262144
#define NBUCKET 8192
#define DEG     32
#define FDIM    128   // in_feats == out_feats == 128

typedef float f32x4 __attribute__((ext_vector_type(4)));
typedef short s16x8 __attribute__((ext_vector_type(8)));
typedef short s16x4 __attribute__((ext_vector_type(4)));

typedef const __attribute__((address_space(1))) unsigned g_u32;
typedef __attribute__((address_space(3))) unsigned l_u32;

__device__ __forceinline__ short f2bf(float f) {
    __hip_bfloat16 h = __float2bfloat16(f);      // RNE, HW cvt
    return *reinterpret_cast<short*>(&h);
}
__device__ __forceinline__ float bf2f(short s) {
    union { unsigned u; float f; } v; v.u = ((unsigned)(unsigned short)s) << 16;
    return v.f;
}

// LDS weight layout: row n (0..127), col k (0..127) bf16 at
//   byte = ((n<<8) + (k<<1)) ^ ((n&7)<<4)      (XOR swizzle on 16B granules)
__device__ __forceinline__ s16x8 read_wfrag(const short* w_lds, int n, int k0) {
    int byte = ((n << 8) + (k0 << 1)) ^ ((n & 7) << 4);
    return *reinterpret_cast<const s16x8*>(reinterpret_cast<const char*>(w_lds) + byte);
}

// f32 staging fallback (R1-style) for the no-workspace path
__device__ __forceinline__ void stage_w(short* w_lds, const float* __restrict__ Wg,
                                        int stride, int tid) {
    #pragma unroll
    for (int it = 0; it < 16; ++it) {
        int i  = it * 256 + tid;
        int n  = i >> 5;
        int k4 = (i & 31) << 2;
        const float4 v = *reinterpret_cast<const float4*>(Wg + (size_t)n * stride + k4);
        s16x4 h; h[0]=f2bf(v.x); h[1]=f2bf(v.y); h[2]=f2bf(v.z); h[3]=f2bf(v.w);
        int byte = ((n << 8) + (k4 << 1)) ^ ((n & 7) << 4);
        *reinterpret_cast<s16x4*>(reinterpret_cast<char*>(w_lds) + byte) = h;
    }
}

// DMA 32 KB of pre-swizzled bf16 weights into LDS (256-thread block).
__device__ __forceinline__ void dma_w32k(const short* __restrict__ gsw, short* lds, int tid) {
    const int lane = tid & 63, wid = tid >> 6;           // 4 waves
    const char* g = reinterpret_cast<const char*>(gsw);
    char* l = reinterpret_cast<char*>(lds);
    #pragma unroll
    for (int i = 0; i < 8; ++i) {
        const int off = i * 4096 + wid * 1024;           // + lane*16 by HW on LDS side
        __builtin_amdgcn_global_load_lds((g_u32*)(g + off + lane * 16),
                                         (l_u32*)(l + off), 16, 0, 0);
    }
}

// ---------------------------------------------------------------------------
// Prep: W_time/W_self/W_neigh f32 -> bf16 PRE-SWIZZLED (4 x 32 KB regions).
// ---------------------------------------------------------------------------
__global__ void prep_kernel(const float* __restrict__ W_time,
                            const float* __restrict__ W_self,
                            const float* __restrict__ W_neigh,
                            short* __restrict__ Wswz)
{
    const int t = blockIdx.x * 256 + threadIdx.x;        // 8192 threads
    const int region = t >> 11;
    const int chunk  = t & 2047;                         // 16B chunk within region
    const int n = chunk >> 4;
    const int c = chunk & 15;                            // k = c*8

    const float* src;
    if      (region == 0) src = W_time  + n * 256 + c * 8;
    else if (region == 1) src = W_time  + n * 256 + 128 + c * 8;
    else if (region == 2) src = W_self  + n * 128 + c * 8;
    else                  src = W_neigh + n * 128 + c * 8;

    const float4 lo = *reinterpret_cast<const float4*>(src);
    const float4 hi = *reinterpret_cast<const float4*>(src + 4);
    s16x8 h;
    h[0]=f2bf(lo.x); h[1]=f2bf(lo.y); h[2]=f2bf(lo.z); h[3]=f2bf(lo.w);
    h[4]=f2bf(hi.x); h[5]=f2bf(hi.y); h[6]=f2bf(hi.z); h[7]=f2bf(hi.w);

    const int byte = (region << 15) + ((((n << 8) + (c << 4)) ^ ((n & 7) << 4)));
    *reinterpret_cast<s16x8*>(reinterpret_cast<char*>(Wswz) + byte) = h;
}

// ---------------------------------------------------------------------------
// Phase 1 (R13): R8 encode with the VGPR cap fixed.
// Empirical law (R9-R12): 2nd launch-bounds arg at 512 thr caps VGPR at
// 256/arg (floor 128): (512,4) -> 64.  R4-R8 ran at 64 VGPR while peak live
// here is ~110 regs (16 float4 banks + tf + frags) -> silent scratch spill.
// (512,2) -> 128-VGPR cap: fits, and occupancy is unchanged anyway because
// LDS (64 KB) already limits to 2 blocks/CU = 16 waves/CU.
// ---------------------------------------------------------------------------
__global__ __launch_bounds__(512, 2)
void encode_kernel(const float* __restrict__ src_feat,
                   const float* __restrict__ dst_feat,
                   const float* __restrict__ ts,
                   const float* __restrict__ freq,
                   const float* __restrict__ ph,
                   const short* __restrict__ Wswz,     // regions 0,1 (64 KB)
                   const float* __restrict__ b_time,
                   short* __restrict__ enc_src,
                   short* __restrict__ enc_dst)
{
    __shared__ short w_lds[2][128 * 128];   // 64 KB: [0]=W1, [1]=W2 (swizzled)

    const int tid  = threadIdx.x;
    const int lane = tid & 63;
    const int wid  = tid >> 6;              // 0..7
    const int lrow = lane & 15;             // edge row within wave tile
    const int q    = lane >> 4;             // channel quadrant
    const int klo  = q << 3;
    const int r0   = blockIdx.x * 128 + wid * 16;

    // 1) issue feat loads (oldest vmcnt entries; drain at the barrier)
    float4 sf[8], df[8];
    #pragma unroll
    for (int kb = 0; kb < 4; ++kb) {
        const float* ps = src_feat + (size_t)(r0 + lrow) * FDIM + kb * 32 + klo;
        const float* pd = dst_feat + (size_t)(r0 + lrow) * FDIM + kb * 32 + klo;
        sf[kb*2]   = *reinterpret_cast<const float4*>(ps);
        sf[kb*2+1] = *reinterpret_cast<const float4*>(ps + 4);
        df[kb*2]   = *reinterpret_cast<const float4*>(pd);
        df[kb*2+1] = *reinterpret_cast<const float4*>(pd + 4);
    }

    // 2) DMA both W halves (64 KB): 8 waves x 8 x 1 KB
    {
        const char* g = reinterpret_cast<const char*>(Wswz);
        char* l = reinterpret_cast<char*>(&w_lds[0][0]);
        #pragma unroll
        for (int i = 0; i < 8; ++i) {
            const int off = i * 8192 + wid * 1024;
            __builtin_amdgcn_global_load_lds((g_u32*)(g + off + lane * 16),
                                             (l_u32*)(l + off), 16, 0, 0);
        }
    }

    // 3) time fragments (VALU, overlaps the loads)
    const float t_row = ts[r0 + lrow];
    s16x8 tf[4];
    #pragma unroll
    for (int kb = 0; kb < 4; ++kb) {
        s16x8 t;
        #pragma unroll
        for (int j = 0; j < 8; ++j) {
            const int k = kb * 32 + klo + j;
            t[j] = f2bf(__cosf(fmaf(t_row, freq[k], ph[k])));
        }
        tf[kb] = t;
    }

    // 4) cvt feat to bf16 fragments (waits feat loads), then barrier
    s16x8 as_[4], ad_[4];
    #pragma unroll
    for (int kb = 0; kb < 4; ++kb) {
        s16x8 a, b;
        #pragma unroll
        for (int j = 0; j < 4; ++j) {
            a[j]   = f2bf(sf[kb*2][j]);   a[4+j] = f2bf(sf[kb*2+1][j]);
            b[j]   = f2bf(df[kb*2][j]);   b[4+j] = f2bf(df[kb*2+1][j]);
        }
        as_[kb] = a; ad_[kb] = b;
    }
    __syncthreads();

    // 5) per-nt (SWAPPED operands): packed 8B stores
    #pragma unroll
    for (int nt = 0; nt < 8; ++nt) {
        const int n = nt * 16 + lrow;
        f32x4 a = {0.f, 0.f, 0.f, 0.f};
        #pragma unroll
        for (int kb = 0; kb < 4; ++kb)
            a = __builtin_amdgcn_mfma_f32_16x16x32_bf16(
                    read_wfrag(w_lds[1], n, kb * 32 + klo), tf[kb], a, 0, 0, 0);
        f32x4 b = a;
        #pragma unroll
        for (int kb = 0; kb < 4; ++kb) {
            const s16x8 wf = read_wfrag(w_lds[0], n, kb * 32 + klo);
            a = __builtin_amdgcn_mfma_f32_16x16x32_bf16(wf, as_[kb], a, 0, 0, 0);
            b = __builtin_amdgcn_mfma_f32_16x16x32_bf16(wf, ad_[kb], b, 0, 0, 0);
        }
        const int ch = nt * 16 + q * 4;
        const float4 bias4 = *reinterpret_cast<const float4*>(b_time + ch);
        s16x4 ss, sd;
        #pragma unroll
        for (int r = 0; r < 4; ++r) {
            float es = a[r] + bias4[r]; es = es > 0.f ? es : 0.f;
            float ed = b[r] + bias4[r]; ed = ed > 0.f ? ed : 0.f;
            ss[r] = f2bf(es); sd[r] = f2bf(ed);
        }
        *reinterpret_cast<s16x4*>(enc_src + (size_t)(r0 + lrow) * FDIM + ch) = ss;
        *reinterpret_cast<s16x4*>(enc_dst + (size_t)(r0 + lrow) * FDIM + ch) = sd;
    }
}

// Fallback encode (R1 structure, f32 staging) if workspace lacks Wswz room.
__global__ __launch_bounds__(256, 2)
void encode_fallback(const float* __restrict__ src_feat,
                     const float* __restrict__ dst_feat,
                     const float* __restrict__ ts,
                     const float* __restrict__ freq,
                     const float* __restrict__ ph,
                     const float* __restrict__ W_time,
                     const float* __restrict__ b_time,
                     short* __restrict__ enc_src,
                     short* __restrict__ enc_dst)
{
    __shared__ short w_lds[128 * 128];
    const int tid  = threadIdx.x;
    const int lane = tid & 63;
    const int wid  = tid >> 6;
    const int r0   = blockIdx.x * 64 + wid * 16;
    const int lrow = lane & 15;
    const int klo  = (lane >> 4) << 3;

    stage_w(w_lds, W_time + 128, 256, tid);
    const float t_row = ts[r0 + lrow];
    s16x8 tf[4];
    #pragma unroll
    for (int kb = 0; kb < 4; ++kb) {
        const int k = kb * 32 + klo;
        s16x8 t;
        #pragma unroll
        for (int j = 0; j < 8; ++j)
            t[j] = f2bf(__cosf(fmaf(t_row, freq[k + j], ph[k + j])));
        tf[kb] = t;
    }
    __syncthreads();
    f32x4 S[8];
    #pragma unroll
    for (int nt = 0; nt < 8; ++nt) {
        f32x4 a = {0.f, 0.f, 0.f, 0.f};
        #pragma unroll
        for (int kb = 0; kb < 4; ++kb)
            a = __builtin_amdgcn_mfma_f32_16x16x32_bf16(
                    tf[kb], read_wfrag(w_lds, nt * 16 + lrow, kb * 32 + klo), a, 0, 0, 0);
        S[nt] = a;
    }
    __syncthreads();
    stage_w(w_lds, W_time, 256, tid);
    __syncthreads();
    #pragma unroll
    for (int s = 0; s < 2; ++s) {
        const float* feat = s ? dst_feat : src_feat;
        short*       enc  = s ? enc_dst  : enc_src;
        s16x8 af[4];
        #pragma unroll
        for (int kb = 0; kb < 4; ++kb) {
            const float* p = feat + (size_t)(r0 + lrow) * FDIM + kb * 32 + klo;
            const float4 lo = *reinterpret_cast<const float4*>(p);
            const float4 hi = *reinterpret_cast<const float4*>(p + 4);
            s16x8 a;
            a[0]=f2bf(lo.x); a[1]=f2bf(lo.y); a[2]=f2bf(lo.z); a[3]=f2bf(lo.w);
            a[4]=f2bf(hi.x); a[5]=f2bf(hi.y); a[6]=f2bf(hi.z); a[7]=f2bf(hi.w);
            af[kb] = a;
        }
        #pragma unroll
        for (int nt = 0; nt < 8; ++nt) {
            f32x4 acc = S[nt];
            #pragma unroll
            for (int kb = 0; kb < 4; ++kb)
                acc = __builtin_amdgcn_mfma_f32_16x16x32_bf16(
                        af[kb], read_wfrag(w_lds, nt * 16 + lrow, kb * 32 + klo), acc, 0, 0, 0);
            const int col  = nt * 16 + lrow;
            const float bias = b_time[col];
            const int rbase = r0 + ((lane >> 4) << 2);
            #pragma unroll
            for (int r = 0; r < 4; ++r) {
                float e = acc[r] + bias;
                e = e > 0.f ? e : 0.f;
                enc[(size_t)(rbase + r) * FDIM + col] = f2bf(e);
            }
        }
    }
}

// ---------------------------------------------------------------------------
// Phase 2: R5 conv VERBATIM — per-bucket causal mean conv + scatter.
// ---------------------------------------------------------------------------
template<int DMA>
__global__ __launch_bounds__(256, 3)
void conv_kernel(const short* __restrict__ enc_src,
                 const short* __restrict__ enc_dst,
                 const short* __restrict__ Wswz_self,   // DMA=1
                 const short* __restrict__ Wswz_neigh,  // DMA=1
                 const float* __restrict__ W_self,      // DMA=0
                 const float* __restrict__ W_neigh,     // DMA=0
                 const float* __restrict__ b_self,
                 const float* __restrict__ b_neigh,
                 const int* __restrict__ src_perm,
                 const int* __restrict__ dst_perm,
                 const int* __restrict__ src_idx,
                 const int* __restrict__ dst_idx,
                 float* __restrict__ out)        // [2][E][128] f32
{
    __shared__ short w_lds[128 * 128];   // 32 KB: Wself -> Wneigh -> f32 epilogue
    __shared__ short hf[2][DEG * 128];   // 16 KB, swizzled rows
    __shared__ int   perm_s[2][DEG];
    __shared__ int   idx_s[2][DEG];
    __shared__ float bias_s[128];

    const int tid = threadIdx.x;
    const int g   = blockIdx.y;
    const int b0  = blockIdx.x * 2;

    const short* enc_self  = g ? enc_dst : enc_src;
    const short* enc_neigh = g ? enc_src : enc_dst;
    const int*   perm      = g ? dst_perm : src_perm;
    const int*   degi      = g ? dst_idx  : src_idx;
    float*       outg      = out + (size_t)g * E_EDGES * FDIM;

    if (DMA) dma_w32k(Wswz_self, w_lds, tid);

    if (tid < 64) {
        const int lb = tid >> 5, d = tid & 31;
        perm_s[lb][d] = perm[(b0 + lb) * DEG + d];
        idx_s[lb][d]  = degi[(b0 + lb) * DEG + d];
    } else if (tid < 192) {
        const int c = tid - 64;
        bias_s[c] = b_self[c] + b_neigh[c];
    }
    if (!DMA) stage_w(w_lds, W_self, 128, tid);
    __syncthreads();

    const int lane = tid & 63;
    const int wid  = tid >> 6;
    const int lb   = wid >> 1;
    const int mt   = wid & 1;
    const int lrow = lane & 15;
    const int klo  = (lane >> 4) << 3;
    const int row  = mt * 16 + lrow;

    // Issue pass-A self-gather FIRST (pass A then waits only these)
    s16x8 hsf[4];
    {
        const int e = perm_s[lb][row];
        const short* p = enc_self + (size_t)e * FDIM;
        #pragma unroll
        for (int kb = 0; kb < 4; ++kb)
            hsf[kb] = *reinterpret_cast<const s16x8*>(p + kb * 32 + klo);
    }

    // Issue ALL cumsum row gathers (independent; land during pass-A MFMA)
    const int lbc = tid >> 7;          // bucket for cumsum role
    const int c   = tid & 127;         // channel
    unsigned short cum[DEG];
    #pragma unroll
    for (int d = 0; d < DEG; ++d) {
        const int e = perm_s[lbc][d];
        cum[d] = *reinterpret_cast<const unsigned short*>(
                     enc_neigh + (size_t)e * FDIM + c);
    }

    // pass A: hs @ Wself^T
    f32x4 acc[8];
    #pragma unroll
    for (int nt = 0; nt < 8; ++nt) {
        f32x4 a = {0.f, 0.f, 0.f, 0.f};
        #pragma unroll
        for (int kb = 0; kb < 4; ++kb)
            a = __builtin_amdgcn_mfma_f32_16x16x32_bf16(
                    hsf[kb], read_wfrag(w_lds, nt * 16 + lrow, kb * 32 + klo), a, 0, 0, 0);
        acc[nt] = a;
    }

    // cumsum accumulate -> hf (values already in registers)
    {
        float run = 0.f;
        #pragma unroll
        for (int d = 0; d < DEG; ++d) {
            run += bf2f((short)cum[d]);
            const float inv = __builtin_amdgcn_rcpf((float)(idx_s[lbc][d] + 1));
            const int byte = ((d << 8) + (c << 1)) ^ ((d & 7) << 4);
            *reinterpret_cast<short*>(reinterpret_cast<char*>(hf[lbc]) + byte)
                = f2bf(run * inv);
        }
    }

    __syncthreads();
    if (DMA) dma_w32k(Wswz_neigh, w_lds, tid);
    else     stage_w(w_lds, W_neigh, 128, tid);
    __syncthreads();

    // pass B: hf[idx[row]] @ Wneigh^T
    s16x8 mff[4];
    {
        const int j = idx_s[lb][row];
        #pragma unroll
        for (int kb = 0; kb < 4; ++kb) {
            const int byte = ((j << 8) + ((kb * 32 + klo) << 1)) ^ ((j & 7) << 4);
            mff[kb] = *reinterpret_cast<const s16x8*>(
                          reinterpret_cast<const char*>(hf[lb]) + byte);
        }
    }
    #pragma unroll
    for (int nt = 0; nt < 8; ++nt) {
        f32x4 a = acc[nt];
        #pragma unroll
        for (int kb = 0; kb < 4; ++kb)
            a = __builtin_amdgcn_mfma_f32_16x16x32_bf16(
                    mff[kb], read_wfrag(w_lds, nt * 16 + lrow, kb * 32 + klo), a, 0, 0, 0);
        acc[nt] = a;
    }

    // epilogue: transpose via w_lds (now free) -> float4 scatter stores
    __syncthreads();
    {
        float* epl = reinterpret_cast<float*>(w_lds) + wid * 2048;  // 16x128 f32
        #pragma unroll
        for (int nt = 0; nt < 8; ++nt) {
            const int col = nt * 16 + lrow;
            const float bias = bias_s[col];
            #pragma unroll
            for (int r = 0; r < 4; ++r) {
                const int rtile = ((lane >> 4) << 2) + r;
                epl[rtile * 128 + col] = acc[nt][r] + bias;
            }
        }
        asm volatile("s_waitcnt lgkmcnt(0)" ::: "memory");
        __builtin_amdgcn_sched_barrier(0);
        #pragma unroll
        for (int i = 0; i < 8; ++i) {
            const int rtile = i * 2 + (lane >> 5);
            const int c4    = (lane & 31) * 4;
            const f32x4 v = *reinterpret_cast<const f32x4*>(epl + rtile * 128 + c4);
            const int e = perm_s[lb][mt * 16 + rtile];
            *reinterpret_cast<f32x4*>(outg + (size_t)e * FDIM + c4) = v;
        }
    }
}

extern "C" void kernel_launch(void* const* d_in, const int* in_sizes, int n_in,
                              void* d_out, int out_size, void* d_ws, size_t ws_size,
                              hipStream_t stream) {
    (void)in_sizes; (void)n_in; (void)out_size;

    const float* src_feat = (const float*)d_in[0];
    const float* dst_feat = (const float*)d_in[1];
    const float* ts       = (const float*)d_in[2];
    const float* freq     = (const float*)d_in[3];
    const float* ph       = (const float*)d_in[4];
    const float* W_time   = (const float*)d_in[5];
    const float* b_time   = (const float*)d_in[6];
    const float* W_self   = (const float*)d_in[7];
    const float* b_self   = (const float*)d_in[8];
    const float* W_neigh  = (const float*)d_in[9];
    const float* b_neigh  = (const float*)d_in[10];
    const int*   src_perm = (const int*)d_in[11];
    const int*   dst_perm = (const int*)d_in[12];
    const int*   src_idx  = (const int*)d_in[13];
    const int*   dst_idx  = (const int*)d_in[14];

    // workspace: enc_src, enc_dst bf16 [E][128] (128 MiB) + Wswz (128 KiB)
    short* enc_src = (short*)d_ws;
    short* enc_dst = enc_src + (size_t)E_EDGES * FDIM;
    short* Wswz    = enc_dst + (size_t)E_EDGES * FDIM;
    const size_t need = (size_t)E_EDGES * FDIM * 2 * 2 + 4 * 32768;

    if (ws_size >= need) {
        prep_kernel<<<dim3(32), dim3(256), 0, stream>>>(W_time, W_self, W_neigh, Wswz);
        encode_kernel<<<dim3(E_EDGES / 128), dim3(512), 0, stream>>>(
            src_feat, dst_feat, ts, freq, ph, Wswz, b_time, enc_src, enc_dst);
        conv_kernel<1><<<dim3(NBUCKET / 2, 2), dim3(256), 0, stream>>>(
            enc_src, enc_dst, Wswz + 2 * 16384, Wswz + 3 * 16384, W_self, W_neigh,
            b_self, b_neigh, src_perm, dst_perm, src_idx, dst_idx, (float*)d_out);
    } else {
        encode_fallback<<<dim3(E_EDGES / 64), dim3(256), 0, stream>>>(
            src_feat, dst_feat, ts, freq, ph, W_time, b_time, enc_src, enc_dst);
        conv_kernel<0><<<dim3(NBUCKET / 2, 2), dim3(256), 0, stream>>>(
            enc_src, enc_dst, (const short*)nullptr, (const short*)nullptr,
            W_self, W_neigh, b_self, b_neigh,
            src_perm, dst_perm, src_idx, dst_idx, (float*)d_out);
    }
}